// Round 2
// baseline (344.044 us; speedup 1.0000x reference)
//
#include <hip/hip_runtime.h>

#define EMBED 64
#define W1_STRIDE 132   // padded stride (floats): 16B-aligned rows, phase-uniform banks

// ---------------------------------------------------------------------------
// Kernel 1: sorted seg_ids -> row_start[B+1] (CSR offsets). Unchanged (cheap,
// verified); kept separate so the fused-kernel change is the only variable.
// ---------------------------------------------------------------------------
__global__ void seg_offsets_kernel(const int* __restrict__ seg, int E, int B,
                                   int* __restrict__ row_start) {
    int e = blockIdx.x * blockDim.x + threadIdx.x;
    if (e >= E) return;
    int s1 = seg[e];
    if (e == 0) {
        for (int s = 0; s <= s1; ++s) row_start[s] = 0;
    } else {
        int s0 = seg[e - 1];
        for (int s = s0 + 1; s <= s1; ++s) row_start[s] = e;
    }
    if (e == E - 1) {
        for (int s = s1 + 1; s <= B; ++s) row_start[s] = E;
    }
}

__device__ __forceinline__ float4 ld_row(const float* __restrict__ features,
                                         int rid, int q) {
    return ((const float4*)(features + ((size_t)rid << 6)))[q];
}

// ---------------------------------------------------------------------------
// Kernel 2 v2b: one wave = ONE PAIR of rows (b, b + B/2), no grid-stride loop.
// (v2 resubmit — round-1 bench died on container acquisition, not the kernel.
//  Only change: defensive zero-init of conditional float4 temporaries.)
//
// MLP restructure vs v1 (which was latency-bound at ~64 VGPRs / 4 loads in
// flight): prologue issues ALL independent globals (bounds x2, nodes x2,
// self-rows x2, id-vectors x2) BEFORE the w1 staging loop so their latency
// hides under staging+sync; the two rows' gathers are interleaved at 16-edge
// group granularity -> 8 float4 row-loads in flight per wave; the two
// matvecs share each w1 LDS read (halves w1 LDS traffic, 2x FMA ILP).
//
// CORRECTNESS INVARIANT: every __shfl executes with all 64 lanes active.
// All branches containing shuffles are WAVE-UNIFORM (derived only from
// wave-uniform gid/row_start values); ragged coverage is handled by
// predicating the accumulate, never the loop/branch. Per-row FP add order
// is identical to v1 (A/B only interleave across rows) -> same absmax.
// ---------------------------------------------------------------------------
__global__ __launch_bounds__(512, 6) void social_encoder_fused(
    const int*   __restrict__ nodes,
    const int*   __restrict__ neigh_ids,
    const int*   __restrict__ row_start,
    const float* __restrict__ features,
    const float* __restrict__ w1,
    const float* __restrict__ b1,
    float*       __restrict__ out,
    int B)
{
    __shared__ float w1s[EMBED * W1_STRIDE];   // 33 KB; row j at w1s[j*132+c]
    __shared__ float comb[8][2][2 * EMBED];    // 8 KB; per-wave, per-row [self|mean]

    const int wave = threadIdx.x >> 6;
    const int lane = threadIdx.x & 63;
    const int q    = lane & 15;   // float4 slot within a 64-float row
    const int sub  = lane >> 4;   // 4 concurrent edge slots

    const int half = (B + 1) >> 1;
    const int gid  = blockIdx.x * 8 + wave;
    const int bA   = gid;
    const int bB   = gid + half;
    const bool hasA = bA < half;
    const bool hasB = bB < B;

    // ---- prologue: issue every independent global load before staging ----
    int sA = 0, eA = 0, sB = 0, eB = 0;
    int nodeA = 0, nodeB = 0;
    if (hasA) { sA = row_start[bA]; eA = row_start[bA + 1]; nodeA = nodes[bA]; }
    if (hasB) { sB = row_start[bB]; eB = row_start[bB + 1]; nodeB = nodes[bB]; }

    float4 svA = make_float4(0.f, 0.f, 0.f, 0.f), svB = svA;
    if (hasA) svA = ld_row(features, nodeA, q);
    if (hasB) svB = ld_row(features, nodeB, q);

    const int nA0 = min(64, eA - sA);   // 0 when !hasA
    const int nB0 = min(64, eB - sB);
    int idA = 0, idB = 0;
    if (lane < nA0) idA = neigh_ids[sA + lane];   // one coalesced load per row
    if (lane < nB0) idB = neigh_ids[sB + lane];

    // ---- stage w1 into LDS (float4, coalesced); hides prologue latency ----
    for (int i = threadIdx.x; i < EMBED * 32; i += 512) {
        const int row = i >> 5;
        const int c4  = (i & 31) << 2;
        *(float4*)&w1s[row * W1_STRIDE + c4] = *(const float4*)(w1 + (row << 7) + c4);
    }
    __syncthreads();   // only cross-wave barrier in the kernel

    const float bj = b1[lane];

    float4 accA = make_float4(0.f, 0.f, 0.f, 0.f), accB = accA;
    const float4 fzero = make_float4(0.f, 0.f, 0.f, 0.f);

    // ---- chunk 0 of both rows, merged at group level: 8 loads in flight ----
    const int nfA = nA0 & ~15, nfB = nB0 & ~15;
    const int gA = nfA >> 4, gB = nfB >> 4;
    const int gmax = max(gA, gB);
    for (int g = 0; g < gmax; ++g) {
        const int base = g << 4;
        const bool doA = g < gA, doB = g < gB;   // wave-uniform
        float4 a0 = fzero, a1 = fzero, a2 = fzero, a3 = fzero;
        float4 c0 = fzero, c1 = fzero, c2 = fzero, c3 = fzero;
        if (doA) {
            const int r0 = __shfl(idA, base + sub,      64);
            const int r1 = __shfl(idA, base + sub + 4,  64);
            const int r2 = __shfl(idA, base + sub + 8,  64);
            const int r3 = __shfl(idA, base + sub + 12, 64);
            a0 = ld_row(features, r0, q); a1 = ld_row(features, r1, q);
            a2 = ld_row(features, r2, q); a3 = ld_row(features, r3, q);
        }
        if (doB) {
            const int r0 = __shfl(idB, base + sub,      64);
            const int r1 = __shfl(idB, base + sub + 4,  64);
            const int r2 = __shfl(idB, base + sub + 8,  64);
            const int r3 = __shfl(idB, base + sub + 12, 64);
            c0 = ld_row(features, r0, q); c1 = ld_row(features, r1, q);
            c2 = ld_row(features, r2, q); c3 = ld_row(features, r3, q);
        }
        if (doA) {
            accA.x += (a0.x + a1.x) + (a2.x + a3.x);
            accA.y += (a0.y + a1.y) + (a2.y + a3.y);
            accA.z += (a0.z + a1.z) + (a2.z + a3.z);
            accA.w += (a0.w + a1.w) + (a2.w + a3.w);
        }
        if (doB) {
            accB.x += (c0.x + c1.x) + (c2.x + c3.x);
            accB.y += (c0.y + c1.y) + (c2.y + c3.y);
            accB.z += (c0.z + c1.z) + (c2.z + c3.z);
            accB.w += (c0.w + c1.w) + (c2.w + c3.w);
        }
    }

    // ---- tails (r in [0,15] each), merged; predicate the ACCUMULATE ----
    {
        const int tA = ((nA0 - nfA) + 3) >> 2;
        const int tB = ((nB0 - nfB) + 3) >> 2;
        const int tmax = max(tA, tB);
        for (int t = 0; t < tmax; ++t) {
            const bool dA = t < tA, dB = t < tB;   // wave-uniform
            float4 va = fzero, vb = fzero;
            int sa = 0, sb = 0;
            if (dA) {
                sa = nfA + sub + 4 * t;            // <= 48+3+12 = 63
                va = ld_row(features, __shfl(idA, sa, 64), q);
            }
            if (dB) {
                sb = nfB + sub + 4 * t;
                vb = ld_row(features, __shfl(idB, sb, 64), q);
            }
            if (dA && sa < nA0) { accA.x += va.x; accA.y += va.y; accA.z += va.z; accA.w += va.w; }
            if (dB && sb < nB0) { accB.x += vb.x; accB.y += vb.y; accB.z += vb.z; accB.w += vb.w; }
        }
    }

    // ---- overflow chunks (rows with >64 edges; Poisson(32) -> ~never) ----
    for (int chunk = sA + 64; chunk < eA; chunk += 64) {
        const int n = min(64, eA - chunk);
        int myid = 0;
        if (lane < n) myid = neigh_ids[chunk + lane];
        const int nfull = n & ~15;
        for (int base = 0; base < nfull; base += 16) {
            const int r0 = __shfl(myid, base + sub,      64);
            const int r1 = __shfl(myid, base + sub + 4,  64);
            const int r2 = __shfl(myid, base + sub + 8,  64);
            const int r3 = __shfl(myid, base + sub + 12, 64);
            const float4 v0 = ld_row(features, r0, q);
            const float4 v1 = ld_row(features, r1, q);
            const float4 v2 = ld_row(features, r2, q);
            const float4 v3 = ld_row(features, r3, q);
            accA.x += (v0.x + v1.x) + (v2.x + v3.x);
            accA.y += (v0.y + v1.y) + (v2.y + v3.y);
            accA.z += (v0.z + v1.z) + (v2.z + v3.z);
            accA.w += (v0.w + v1.w) + (v2.w + v3.w);
        }
        const int tmax = ((n - nfull) + 3) >> 2;
        for (int t = 0; t < tmax; ++t) {
            const int src = nfull + sub + 4 * t;
            const int rid = __shfl(myid, src, 64);
            const float4 v = ld_row(features, rid, q);
            if (src < n) { accA.x += v.x; accA.y += v.y; accA.z += v.z; accA.w += v.w; }
        }
    }
    for (int chunk = sB + 64; chunk < eB; chunk += 64) {
        const int n = min(64, eB - chunk);
        int myid = 0;
        if (lane < n) myid = neigh_ids[chunk + lane];
        const int nfull = n & ~15;
        for (int base = 0; base < nfull; base += 16) {
            const int r0 = __shfl(myid, base + sub,      64);
            const int r1 = __shfl(myid, base + sub + 4,  64);
            const int r2 = __shfl(myid, base + sub + 8,  64);
            const int r3 = __shfl(myid, base + sub + 12, 64);
            const float4 v0 = ld_row(features, r0, q);
            const float4 v1 = ld_row(features, r1, q);
            const float4 v2 = ld_row(features, r2, q);
            const float4 v3 = ld_row(features, r3, q);
            accB.x += (v0.x + v1.x) + (v2.x + v3.x);
            accB.y += (v0.y + v1.y) + (v2.y + v3.y);
            accB.z += (v0.z + v1.z) + (v2.z + v3.z);
            accB.w += (v0.w + v1.w) + (v2.w + v3.w);
        }
        const int tmax = ((n - nfull) + 3) >> 2;
        for (int t = 0; t < tmax; ++t) {
            const int src = nfull + sub + 4 * t;
            const int rid = __shfl(myid, src, 64);
            const float4 v = ld_row(features, rid, q);
            if (src < n) { accB.x += v.x; accB.y += v.y; accB.z += v.z; accB.w += v.w; }
        }
    }

    // ---- reduce the 4 sub-groups for both rows (full wave active) ----
    accA.x += __shfl_xor(accA.x, 16, 64); accA.x += __shfl_xor(accA.x, 32, 64);
    accA.y += __shfl_xor(accA.y, 16, 64); accA.y += __shfl_xor(accA.y, 32, 64);
    accA.z += __shfl_xor(accA.z, 16, 64); accA.z += __shfl_xor(accA.z, 32, 64);
    accA.w += __shfl_xor(accA.w, 16, 64); accA.w += __shfl_xor(accA.w, 32, 64);
    accB.x += __shfl_xor(accB.x, 16, 64); accB.x += __shfl_xor(accB.x, 32, 64);
    accB.y += __shfl_xor(accB.y, 16, 64); accB.y += __shfl_xor(accB.y, 32, 64);
    accB.z += __shfl_xor(accB.z, 16, 64); accB.z += __shfl_xor(accB.z, 32, 64);
    accB.w += __shfl_xor(accB.w, 16, 64); accB.w += __shfl_xor(accB.w, 32, 64);

    const float sclA = 1.0f / fmaxf((float)(eA - sA), 1.0f);
    const float sclB = 1.0f / fmaxf((float)(eB - sB), 1.0f);
    float4 nvA, nvB;
    nvA.x = accA.x * sclA; nvA.y = accA.y * sclA; nvA.z = accA.z * sclA; nvA.w = accA.w * sclA;
    nvB.x = accB.x * sclB; nvB.y = accB.y * sclB; nvB.z = accB.z * sclB; nvB.w = accB.w * sclB;

    // ---- comb = [self(16 float4) | mean-neigh(16 float4)] per row ----
    float* cA = comb[wave][0];
    float* cB = comb[wave][1];
    if (lane < 32) {
        ((float4*)cA)[lane] = (lane < 16) ? svA : nvA;
        ((float4*)cB)[lane] = (lane < 16) ? svB : nvB;
    }
    __threadfence_block();   // same-wave DS ops are HW-ordered; pins compiler order

    // ---- dual matvec: one wv read feeds both rows (2x FMA ILP) ----
    float accdA = bj, accdB = bj;
    const float* wrow = &w1s[lane * W1_STRIDE];
    #pragma unroll 8
    for (int c = 0; c < 2 * EMBED; c += 4) {
        const float4 wv  = *(const float4*)&wrow[c];   // ds_read_b128
        const float4 cvA = *(const float4*)&cA[c];     // broadcast read
        const float4 cvB = *(const float4*)&cB[c];     // broadcast read
        accdA += cvA.x * wv.x + cvA.y * wv.y + cvA.z * wv.z + cvA.w * wv.w;
        accdB += cvB.x * wv.x + cvB.y * wv.y + cvB.z * wv.z + cvB.w * wv.w;
    }
    if (hasA) out[((size_t)bA << 6) + lane] = fmaxf(accdA, 0.0f);
    if (hasB) out[((size_t)bB << 6) + lane] = fmaxf(accdB, 0.0f);
}

extern "C" void kernel_launch(void* const* d_in, const int* in_sizes, int n_in,
                              void* d_out, int out_size, void* d_ws, size_t ws_size,
                              hipStream_t stream) {
    const int*   nodes     = (const int*)d_in[0];
    const int*   neigh_ids = (const int*)d_in[1];
    const int*   seg_ids   = (const int*)d_in[2];
    const float* features  = (const float*)d_in[3];
    const float* w1        = (const float*)d_in[4];
    const float* b1        = (const float*)d_in[5];
    float*       out       = (float*)d_out;

    const int B = in_sizes[0];      // 16384
    const int E = in_sizes[1];      // 524288

    int* row_start = (int*)d_ws;    // (B+1) ints, fully rewritten every call

    seg_offsets_kernel<<<(E + 255) / 256, 256, 0, stream>>>(seg_ids, E, B, row_start);

    const int half = (B + 1) >> 1;
    const int fblocks = (half + 7) / 8;   // one wave per row-pair
    social_encoder_fused<<<fblocks, 512, 0, stream>>>(nodes, neigh_ids, row_start,
                                                      features, w1, b1, out, B);
}

// Round 4
// 333.978 us; speedup vs baseline: 1.0301x; 1.0301x over previous
//
#include <hip/hip_runtime.h>

#define EMBED 64
#define W1_STRIDE 132   // padded stride (floats): 16B-aligned rows, phase-uniform banks

__device__ __forceinline__ float4 ld_row(const float* __restrict__ features,
                                         int rid, int q) {
    return ((const float4*)(features + ((size_t)rid << 6)))[q];
}

// ---------------------------------------------------------------------------
// v3b: resubmit of v3 (round-3 bench died on container acquisition, same
// infra signature as round 1 which cleared on resubmission; kernel audited —
// no unbounded loops, no OOB, no divergent-shfl hazard, no conditional
// barriers).
//
// v3: single fused kernel. Proven v1 per-row body (332 µs structure) with the
// seg_offsets kernel FOLDED IN: each wave computes its two rows' CSR bounds
// via branchless lower_bound binary search over sorted seg_ids (4 boundary
// keys on 4 lanes in parallel, broadcast by __shfl). Saves one dispatch, the
// inter-kernel serialization bubble, and all workspace traffic.
//
// Post-mortem of v2b (344 µs, regression): per-wave ILP interleaving of two
// rows did NOT help — the v1 gather was already TLP-saturated (32 waves/CU,
// ~8192 resident waves each with >=4 KB of loads in flight covers HBM latency
// ~20x over). Reverted to the sequential v1 body, 64-VGPR / 4-blocks-per-CU
// occupancy point.
//
// CORRECTNESS INVARIANT: every __shfl executes with all 64 lanes active.
// All branches containing shuffles are WAVE-UNIFORM (bA/bB/bounds are
// wave-uniform after the __shfl broadcast); ragged coverage is handled by
// predicating the ACCUMULATE, never the loop. The binary-search loop has a
// uniform trip count (sh0..0); its only divergence is the predicated pos
// update (no shuffles inside). Per-row FP add order identical to v1.
// ---------------------------------------------------------------------------
__global__ __launch_bounds__(512, 8) void social_encoder_fused(
    const int*   __restrict__ nodes,
    const int*   __restrict__ neigh_ids,
    const int*   __restrict__ seg,       // sorted seg_ids, length E
    const float* __restrict__ features,
    const float* __restrict__ w1,
    const float* __restrict__ b1,
    float*       __restrict__ out,
    int B, int E)
{
    __shared__ float w1s[EMBED * W1_STRIDE];  // 33 KB; row j at w1s[j*132+c]
    __shared__ float comb[8][2 * EMBED];      // 4 KB; per-wave [self|mean-neigh]

    const int wave = threadIdx.x >> 6;
    const int lane = threadIdx.x & 63;
    const int q    = lane & 15;   // float4 slot within a 64-float row
    const int sub  = lane >> 4;   // 4 concurrent edge slots

    // ---- stage w1 into LDS first: its loads overlap the search chain ----
    for (int i = threadIdx.x; i < EMBED * 32; i += 512) {
        const int row = i >> 5;
        const int c4  = (i & 31) << 2;
        *(float4*)&w1s[row * W1_STRIDE + c4] = *(const float4*)(w1 + (row << 7) + c4);
    }

    // ---- in-kernel CSR bounds: lower_bound(seg, key) for the wave's 4
    //      boundary keys {bA, bA+1, bB, bB+1}, one per lane group (lane&3).
    //      Same 4 addresses replicated across the wave -> coalescer dedups.
    const int waves_total = gridDim.x * 8;     // number of row-pairs
    const int gid = blockIdx.x * 8 + wave;     // wave-uniform
    const int bA  = gid;
    const int bB  = gid + waves_total;
    const int k   = lane & 3;
    const int key = (k == 0) ? bA : (k == 1) ? (bA + 1) : (k == 2) ? bB : (bB + 1);
    int pos = 0;
    const int sh0 = 31 - __clz(E);             // E=2^19 -> sh0=19, 20 steps
    for (int sh = sh0; sh >= 0; --sh) {        // UNIFORM trip count
        const int cand = pos + (1 << sh);
        if (cand <= E) {                       // divergent predicate, no shfl
            if (seg[cand - 1] < key) pos = cand;
        }
    }
    // pos == count of seg values < key == lower_bound index. Broadcast.
    const int sA = __shfl(pos, 0, 64), eA = __shfl(pos, 1, 64);
    const int sB = __shfl(pos, 2, 64), eB = __shfl(pos, 3, 64);

    __syncthreads();   // only cross-wave barrier in the kernel

    const float bj = b1[lane];
    float* cwave = comb[wave];

    #pragma unroll
    for (int rr = 0; rr < 2; ++rr) {
        const int b     = rr ? bB : bA;        // wave-uniform
        const int start = rr ? sB : sA;
        const int end   = rr ? eB : eA;
        if (b < B) {                           // wave-uniform guard
            const int node = nodes[b];
            // Self row issued early so it overlaps the gather chain.
            const float4 sv = ld_row(features, node, q);

            float4 acc = make_float4(0.f, 0.f, 0.f, 0.f);

            for (int chunk = start; chunk < end; chunk += 64) {   // uniform
                const int n = min(64, end - chunk);               // uniform
                int myid = 0;
                if (lane < n) myid = neigh_ids[chunk + lane];     // one coalesced load

                // ---- main: full 16-edge groups, UNIFORM trip count ----
                const int nfull = n & ~15;                        // uniform
                for (int base = 0; base < nfull; base += 16) {
                    const int r0 = __shfl(myid, base + sub,      64);
                    const int r1 = __shfl(myid, base + sub + 4,  64);
                    const int r2 = __shfl(myid, base + sub + 8,  64);
                    const int r3 = __shfl(myid, base + sub + 12, 64);
                    const float4 v0 = ld_row(features, r0, q);
                    const float4 v1 = ld_row(features, r1, q);
                    const float4 v2 = ld_row(features, r2, q);
                    const float4 v3 = ld_row(features, r3, q);
                    acc.x += (v0.x + v1.x) + (v2.x + v3.x);
                    acc.y += (v0.y + v1.y) + (v2.y + v3.y);
                    acc.z += (v0.z + v1.z) + (v2.z + v3.z);
                    acc.w += (v0.w + v1.w) + (v2.w + v3.w);
                }

                // ---- tail: r = n - nfull in [0,15], UNIFORM trip count ----
                const int r = n - nfull;                          // uniform
                const int tmax = (r + 3) >> 2;                    // uniform
                for (int t = 0; t < tmax; ++t) {
                    const int src = nfull + sub + 4 * t;          // <= 63
                    const int rid = __shfl(myid, src, 64);        // all lanes active
                    const float4 v = ld_row(features, rid, q);
                    if (src < n) {   // predicate the ACCUMULATE, not the loop
                        acc.x += v.x; acc.y += v.y; acc.z += v.z; acc.w += v.w;
                    }
                }
            }

            // Reduce the 4 sub-groups (full wave active here).
            acc.x += __shfl_xor(acc.x, 16, 64); acc.x += __shfl_xor(acc.x, 32, 64);
            acc.y += __shfl_xor(acc.y, 16, 64); acc.y += __shfl_xor(acc.y, 32, 64);
            acc.z += __shfl_xor(acc.z, 16, 64); acc.z += __shfl_xor(acc.z, 32, 64);
            acc.w += __shfl_xor(acc.w, 16, 64); acc.w += __shfl_xor(acc.w, 32, 64);

            const float scale = 1.0f / fmaxf((float)(end - start), 1.0f);
            float4 nv;
            nv.x = acc.x * scale; nv.y = acc.y * scale;
            nv.z = acc.z * scale; nv.w = acc.w * scale;

            // comb = [self(16 float4) | neigh(16 float4)], slot = lane (0..31).
            const float4 val = (lane < 16) ? sv : nv;
            if (lane < 32) ((float4*)cwave)[lane] = val;

            __threadfence_block();   // same-wave DS ops are HW-ordered; pins order

            float accd = bj;
            const float* wrow = &w1s[lane * W1_STRIDE];
            #pragma unroll 8
            for (int c = 0; c < 2 * EMBED; c += 4) {
                const float4 cv = *(const float4*)&cwave[c];   // broadcast read
                const float4 wv = *(const float4*)&wrow[c];    // ds_read_b128
                accd += cv.x * wv.x + cv.y * wv.y + cv.z * wv.z + cv.w * wv.w;
            }
            out[((size_t)b << 6) + lane] = fmaxf(accd, 0.0f);

            __threadfence_block();   // row B's comb writes stay after these reads
        }
    }
}

extern "C" void kernel_launch(void* const* d_in, const int* in_sizes, int n_in,
                              void* d_out, int out_size, void* d_ws, size_t ws_size,
                              hipStream_t stream) {
    const int*   nodes     = (const int*)d_in[0];
    const int*   neigh_ids = (const int*)d_in[1];
    const int*   seg_ids   = (const int*)d_in[2];
    const float* features  = (const float*)d_in[3];
    const float* w1        = (const float*)d_in[4];
    const float* b1        = (const float*)d_in[5];
    float*       out       = (float*)d_out;

    const int B = in_sizes[0];      // 16384
    const int E = in_sizes[1];      // 524288

    // One kernel: waves = fblocks*8 row-pairs; rows (gid, gid+waves_total).
    const int fblocks = (B + 15) / 16;   // 1024 for B=16384
    social_encoder_fused<<<fblocks, 512, 0, stream>>>(nodes, neigh_ids, seg_ids,
                                                      features, w1, b1, out, B, E);
}